// Round 1
// baseline (1257.601 us; speedup 1.0000x reference)
//
#include <hip/hip_runtime.h>

#define BB  8
#define CC  64
#define HH  128
#define WW  128
#define OCC 18   // 2*KK offset channels
// kernel K=3, KK=9 taps; offset conv is 5x5 pad 2

// ---------------------------------------------------------------------------
// Tiny kernel: transpose weights (o,c,kk) -> wt[t][c][o] so the einsum inner
// loop reads 8 consecutive floats per (t,c) (coalesced + L1-resident 16KB/tap)
// ---------------------------------------------------------------------------
__global__ __launch_bounds__(256) void transpose_w_kernel(
    const float* __restrict__ w, float* __restrict__ wt)
{
    int idx = blockIdx.x * 256 + threadIdx.x;   // over 64*64*9 = 36864
    if (idx >= CC * 64 * 9) return;
    int o = idx / (64 * 9);
    int r = idx % (64 * 9);
    int c = r / 9;
    int t = r % 9;
    wt[(t * 64 + c) * 64 + o] = w[idx];
}

// ---------------------------------------------------------------------------
// Offset conv: 5x5, C=64 -> 18, zero pad 2, + bias, clip to [-1,1].
// Grid (16 ytiles, 18 oc, 8 b), 256 threads. Thread = 4 consecutive x at one
// (b,oc,y). oc = blockIdx.y => weight addresses wave-uniform => s_load.
// ---------------------------------------------------------------------------
__global__ __launch_bounds__(256) void offset_conv_kernel(
    const float* __restrict__ x, const float* __restrict__ ow,
    const float* __restrict__ ob, float* __restrict__ off)
{
    const int tid = threadIdx.x;
    const int xg  = tid & 31;          // 32 x-groups of 4 px
    const int yo  = tid >> 5;          // 8 rows per block
    const int y   = blockIdx.x * 8 + yo;
    const int oc  = blockIdx.y;
    const int b   = blockIdx.z;
    const int x0  = xg * 4;

    const float bias = ob[oc];
    float a0 = bias, a1 = bias, a2 = bias, a3 = bias;

    // x-border masks/clamps are loop-invariant: precompute once
    float mf[8];
    int   xc[8];
#pragma unroll
    for (int j = 0; j < 8; j++) {
        int xx = x0 + j - 2;
        mf[j] = (xx >= 0 && xx < WW) ? 1.0f : 0.0f;
        xc[j] = xx < 0 ? 0 : (xx > WW - 1 ? WW - 1 : xx);
    }

    const float* xb = x  + (size_t)b * CC * HH * WW;
    const float* wb = ow + oc * CC * 25;

    for (int c = 0; c < CC; c++) {
        const float* xcp = xb + c * HH * WW;
        const float* wc  = wb + c * 25;
#pragma unroll
        for (int ky = 0; ky < 5; ky++) {
            int yy = y + ky - 2;
            if (yy < 0 || yy >= HH) continue;   // zero padding rows
            const float* row = xcp + yy * WW;
            float v[8];
#pragma unroll
            for (int j = 0; j < 8; j++) v[j] = row[xc[j]] * mf[j];
#pragma unroll
            for (int kx = 0; kx < 5; kx++) {
                float wv = wc[ky * 5 + kx];     // uniform -> scalar load
                a0 += v[kx + 0] * wv;
                a1 += v[kx + 1] * wv;
                a2 += v[kx + 2] * wv;
                a3 += v[kx + 3] * wv;
            }
        }
    }

    float4 r;
    r.x = fminf(fmaxf(a0, -1.f), 1.f);
    r.y = fminf(fmaxf(a1, -1.f), 1.f);
    r.z = fminf(fmaxf(a2, -1.f), 1.f);
    r.w = fminf(fmaxf(a3, -1.f), 1.f);
    *(float4*)&off[(((size_t)(b * OCC + oc) * HH + y) << 7) + x0] = r;
}

// ---------------------------------------------------------------------------
// Deformable sampling + einsum. One block per (b, y-row): 128 pixels.
// Per tap t: stage bilinear samples S[c][p] (64x128 fp32, 32KB LDS), then
// mini-GEMM: acc[o 8][p 4] += wt[t][c][o] * S[c][p] over c.
// ---------------------------------------------------------------------------
__global__ __launch_bounds__(256) void deform_kernel(
    const float* __restrict__ x, const float* __restrict__ wt,
    const float* __restrict__ off, float* __restrict__ out)
{
    __shared__ float S[CC * WW];   // 32 KB

    const int tid = threadIdx.x;
    const int b = blockIdx.x >> 7;
    const int y = blockIdx.x & 127;

    // staging role: pixel p, channel half
    const int p     = tid & 127;
    const int chalf = (tid >> 7) * 32;   // 0 or 32

    // einsum role: 8 o-groups x 32 pixel-groups
    const int og = tid >> 5;
    const int o0 = og * 8;
    const int pg = tid & 31;
    const int p4 = pg * 4;

    float acc[8][4];
#pragma unroll
    for (int i = 0; i < 8; i++)
#pragma unroll
        for (int j = 0; j < 4; j++) acc[i][j] = 0.f;

    const float* xb = x + (size_t)b * CC * HH * WW;

    for (int t = 0; t < 9; t++) {
        // ---- bilinear coords for (t, pixel p) — shared by all 64 channels
        float dy = off[(((size_t)(b * OCC + 2 * t    ) * HH + y) << 7) + p];
        float dx = off[(((size_t)(b * OCC + 2 * t + 1) * HH + y) << 7) + p];
        float py = (float)(y + t / 3 - 1) + dy;
        float px = (float)(p + t % 3 - 1) + dx;
        float y0f = floorf(py), x0f = floorf(px);
        float fy = py - y0f, fx = px - x0f;
        int y0 = (int)y0f, xi0 = (int)x0f;
        int y1 = y0 + 1,   xi1 = xi0 + 1;
        float vy0 = (y0  >= 0 && y0  < HH) ? 1.f : 0.f;
        float vy1 = (y1  >= 0 && y1  < HH) ? 1.f : 0.f;
        float vx0 = (xi0 >= 0 && xi0 < WW) ? 1.f : 0.f;
        float vx1 = (xi1 >= 0 && xi1 < WW) ? 1.f : 0.f;
        float gy = 1.f - fy, gx = 1.f - fx;
        float w00 = gy * gx * vy0 * vx0;
        float w01 = gy * fx * vy0 * vx1;
        float w10 = fy * gx * vy1 * vx0;
        float w11 = fy * fx * vy1 * vx1;
        int y0c = y0  < 0 ? 0 : (y0  > HH - 1 ? HH - 1 : y0);
        int y1c = y1  < 0 ? 0 : (y1  > HH - 1 ? HH - 1 : y1);
        int x0c = xi0 < 0 ? 0 : (xi0 > WW - 1 ? WW - 1 : xi0);
        int x1c = xi1 < 0 ? 0 : (xi1 > WW - 1 ? WW - 1 : xi1);
        int i00 = y0c * WW + x0c, i01 = y0c * WW + x1c;
        int i10 = y1c * WW + x0c, i11 = y1c * WW + x1c;

        // ---- stage 32 channels' samples for this pixel into LDS
        const float* img = xb + (size_t)chalf * HH * WW;
#pragma unroll 4
        for (int i = 0; i < 32; i++) {
            float v = w00 * img[i00] + w01 * img[i01]
                    + w10 * img[i10] + w11 * img[i11];
            S[(chalf + i) * WW + p] = v;
            img += HH * WW;
        }
        __syncthreads();

        // ---- mini-GEMM for this tap: acc += wt[t][c][o-tile] * S[c][p-tile]
        const float* wtt = wt + t * CC * 64;
        for (int c = 0; c < CC; c++) {
            float4 s = *(const float4*)&S[c * WW + p4];
            const float4* wp = (const float4*)(wtt + c * 64 + o0);
            float4 wa = wp[0], wb2 = wp[1];
            float wv[8] = {wa.x, wa.y, wa.z, wa.w, wb2.x, wb2.y, wb2.z, wb2.w};
#pragma unroll
            for (int oo = 0; oo < 8; oo++) {
                acc[oo][0] += wv[oo] * s.x;
                acc[oo][1] += wv[oo] * s.y;
                acc[oo][2] += wv[oo] * s.z;
                acc[oo][3] += wv[oo] * s.w;
            }
        }
        __syncthreads();   // before next tap overwrites S
    }

#pragma unroll
    for (int oo = 0; oo < 8; oo++) {
        float4 v;
        v.x = acc[oo][0]; v.y = acc[oo][1]; v.z = acc[oo][2]; v.w = acc[oo][3];
        *(float4*)&out[(((size_t)(b * CC + o0 + oo) * HH + y) << 7) + p4] = v;
    }
}

// ---------------------------------------------------------------------------
extern "C" void kernel_launch(void* const* d_in, const int* in_sizes, int n_in,
                              void* d_out, int out_size, void* d_ws, size_t ws_size,
                              hipStream_t stream)
{
    const float* x  = (const float*)d_in[0];   // (8,64,128,128)
    const float* w  = (const float*)d_in[1];   // (64,64,3,3)
    const float* ow = (const float*)d_in[2];   // (18,64,5,5)
    const float* ob = (const float*)d_in[3];   // (18,)
    float* out = (float*)d_out;                // (8,64,128,128)

    // workspace layout: off (B,18,H,W) fp32 = 9,437,184 B ; wt (9,64,64) fp32
    float* off = (float*)d_ws;
    float* wt  = (float*)((char*)d_ws + (size_t)BB * OCC * HH * WW * 4);

    transpose_w_kernel<<<dim3((CC * 64 * 9 + 255) / 256), 256, 0, stream>>>(w, wt);
    offset_conv_kernel<<<dim3(HH / 8, OCC, BB), 256, 0, stream>>>(x, ow, ob, off);
    deform_kernel<<<dim3(BB * HH), 256, 0, stream>>>(x, wt, off, out);
}

// Round 2
// 978.235 us; speedup vs baseline: 1.2856x; 1.2856x over previous
//
#include <hip/hip_runtime.h>

#define BB  8
#define CC  64
#define HH  128
#define WW  128
#define OCC 18   // 2*KK offset channels
// kernel K=3, KK=9 taps; offset conv is 5x5 pad 2

// ---------------------------------------------------------------------------
// Tiny kernel: transpose weights (o,c,kk) -> wt[t][c][o] so the einsum inner
// loop reads 8 consecutive floats per (t,c) (coalesced + L1-resident 16KB/tap)
// ---------------------------------------------------------------------------
__global__ __launch_bounds__(256) void transpose_w_kernel(
    const float* __restrict__ w, float* __restrict__ wt)
{
    int idx = blockIdx.x * 256 + threadIdx.x;   // over 64*64*9 = 36864
    if (idx >= CC * 64 * 9) return;
    int o = idx / (64 * 9);
    int r = idx % (64 * 9);
    int c = r / 9;
    int t = r % 9;
    wt[(t * 64 + c) * 64 + o] = w[idx];
}

// ---------------------------------------------------------------------------
// Offset conv: 5x5, C=64 -> 18, zero pad 2, + bias, clip to [-1,1].
// Block = one (b,y) row for ALL 18 oc; loop over c staging a 5x132
// zero-padded LDS tile (coalesced), reused by all oc. 256 thr = 128 px x
// 2 oc-halves (9 oc each). Weights wave-uniform -> s_load; 225 FMA / 25
// ds_read per c per thread.
// ---------------------------------------------------------------------------
__global__ __launch_bounds__(256) void offset_conv_kernel(
    const float* __restrict__ x, const float* __restrict__ ow,
    const float* __restrict__ ob, float* __restrict__ off)
{
    __shared__ float S[5 * 132];   // 5 rows x (128 + 2*2 pad) = 2640 B

    const int tid = threadIdx.x;
    const int y = blockIdx.x & 127;
    const int b = blockIdx.x >> 7;

    // --- staging plan: 660 tile elements over 256 threads, 3 slots, all
    //     c-invariant except the channel base pointer
    int   srcoff[3]; float msk[3]; int ldso[3];
#pragma unroll
    for (int k = 0; k < 3; k++) {
        int idx = tid + k * 256;
        if (idx < 5 * 132) {
            int r   = idx / 132;
            int col = idx % 132;
            int yy = y + r - 2;
            int xx = col - 2;
            bool valid = (yy >= 0 && yy < HH && xx >= 0 && xx < WW);
            int yyc = yy < 0 ? 0 : (yy > HH - 1 ? HH - 1 : yy);
            int xxc = xx < 0 ? 0 : (xx > WW - 1 ? WW - 1 : xx);
            srcoff[k] = yyc * WW + xxc;
            msk[k]    = valid ? 1.f : 0.f;
            ldso[k]   = idx;
        } else { ldso[k] = -1; srcoff[k] = 0; msk[k] = 0.f; }
    }

    const int px  = tid & 127;
    const int oc0 = (tid >> 7) * 9;   // wave-uniform (lanes 0..63 same)

    float acc[9];
#pragma unroll
    for (int i = 0; i < 9; i++) acc[i] = ob[oc0 + i];

    const float* xb = x + (size_t)b * CC * HH * WW;

    for (int c = 0; c < CC; c++) {
        const float* xc = xb + c * HH * WW;
        __syncthreads();               // previous compute done before restage
#pragma unroll
        for (int k = 0; k < 3; k++)
            if (ldso[k] >= 0) S[ldso[k]] = xc[srcoff[k]] * msk[k];
        __syncthreads();

        const float* wc = ow + ((size_t)oc0 * CC + c) * 25;  // ow[oc0][c][0][0]
#pragma unroll
        for (int ky = 0; ky < 5; ky++) {
            float v[5];
#pragma unroll
            for (int kx = 0; kx < 5; kx++) v[kx] = S[ky * 132 + px + kx];
#pragma unroll
            for (int i = 0; i < 9; i++) {
                const float* wr = wc + i * (CC * 25) + ky * 5;  // uniform
#pragma unroll
                for (int kx = 0; kx < 5; kx++)
                    acc[i] += v[kx] * wr[kx];
            }
        }
    }

    const size_t obase = (((size_t)b * OCC + oc0) * HH + y) * WW + px;
#pragma unroll
    for (int i = 0; i < 9; i++) {
        float r = fminf(fmaxf(acc[i], -1.f), 1.f);
        off[obase + (size_t)i * HH * WW] = r;
    }
}

// ---------------------------------------------------------------------------
// Deformable sampling + einsum. One block per (b, y-row): 128 pixels.
// Per tap t: stage bilinear samples S[c][p] (64x128 fp32, 32KB LDS), then
// mini-GEMM: acc[o 8][p 4] += wt[t][c][o] * S[c][p] over c.
// ---------------------------------------------------------------------------
__global__ __launch_bounds__(256) void deform_kernel(
    const float* __restrict__ x, const float* __restrict__ wt,
    const float* __restrict__ off, float* __restrict__ out)
{
    __shared__ float S[CC * WW];   // 32 KB

    const int tid = threadIdx.x;
    const int b = blockIdx.x >> 7;
    const int y = blockIdx.x & 127;

    // staging role: pixel p, channel half
    const int p     = tid & 127;
    const int chalf = (tid >> 7) * 32;   // 0 or 32

    // einsum role: 8 o-groups x 32 pixel-groups
    const int og = tid >> 5;
    const int o0 = og * 8;
    const int pg = tid & 31;
    const int p4 = pg * 4;

    float acc[8][4];
#pragma unroll
    for (int i = 0; i < 8; i++)
#pragma unroll
        for (int j = 0; j < 4; j++) acc[i][j] = 0.f;

    const float* xb = x + (size_t)b * CC * HH * WW;

    for (int t = 0; t < 9; t++) {
        // ---- bilinear coords for (t, pixel p) — shared by all 64 channels
        float dy = off[(((size_t)(b * OCC + 2 * t    ) * HH + y) << 7) + p];
        float dx = off[(((size_t)(b * OCC + 2 * t + 1) * HH + y) << 7) + p];
        float py = (float)(y + t / 3 - 1) + dy;
        float px = (float)(p + t % 3 - 1) + dx;
        float y0f = floorf(py), x0f = floorf(px);
        float fy = py - y0f, fx = px - x0f;
        int y0 = (int)y0f, xi0 = (int)x0f;
        int y1 = y0 + 1,   xi1 = xi0 + 1;
        float vy0 = (y0  >= 0 && y0  < HH) ? 1.f : 0.f;
        float vy1 = (y1  >= 0 && y1  < HH) ? 1.f : 0.f;
        float vx0 = (xi0 >= 0 && xi0 < WW) ? 1.f : 0.f;
        float vx1 = (xi1 >= 0 && xi1 < WW) ? 1.f : 0.f;
        float gy = 1.f - fy, gx = 1.f - fx;
        float w00 = gy * gx * vy0 * vx0;
        float w01 = gy * fx * vy0 * vx1;
        float w10 = fy * gx * vy1 * vx0;
        float w11 = fy * fx * vy1 * vx1;
        int y0c = y0  < 0 ? 0 : (y0  > HH - 1 ? HH - 1 : y0);
        int y1c = y1  < 0 ? 0 : (y1  > HH - 1 ? HH - 1 : y1);
        int x0c = xi0 < 0 ? 0 : (xi0 > WW - 1 ? WW - 1 : xi0);
        int x1c = xi1 < 0 ? 0 : (xi1 > WW - 1 ? WW - 1 : xi1);
        int i00 = y0c * WW + x0c, i01 = y0c * WW + x1c;
        int i10 = y1c * WW + x0c, i11 = y1c * WW + x1c;

        // ---- stage 32 channels' samples for this pixel into LDS
        const float* img = xb + (size_t)chalf * HH * WW;
#pragma unroll 4
        for (int i = 0; i < 32; i++) {
            float v = w00 * img[i00] + w01 * img[i01]
                    + w10 * img[i10] + w11 * img[i11];
            S[(chalf + i) * WW + p] = v;
            img += HH * WW;
        }
        __syncthreads();

        // ---- mini-GEMM for this tap: acc += wt[t][c][o-tile] * S[c][p-tile]
        const float* wtt = wt + t * CC * 64;
        for (int c = 0; c < CC; c++) {
            float4 s = *(const float4*)&S[c * WW + p4];
            const float4* wp = (const float4*)(wtt + c * 64 + o0);
            float4 wa = wp[0], wb2 = wp[1];
            float wv[8] = {wa.x, wa.y, wa.z, wa.w, wb2.x, wb2.y, wb2.z, wb2.w};
#pragma unroll
            for (int oo = 0; oo < 8; oo++) {
                acc[oo][0] += wv[oo] * s.x;
                acc[oo][1] += wv[oo] * s.y;
                acc[oo][2] += wv[oo] * s.z;
                acc[oo][3] += wv[oo] * s.w;
            }
        }
        __syncthreads();   // before next tap overwrites S
    }

#pragma unroll
    for (int oo = 0; oo < 8; oo++) {
        float4 v;
        v.x = acc[oo][0]; v.y = acc[oo][1]; v.z = acc[oo][2]; v.w = acc[oo][3];
        *(float4*)&out[(((size_t)(b * CC + o0 + oo) * HH + y) << 7) + p4] = v;
    }
}

// ---------------------------------------------------------------------------
extern "C" void kernel_launch(void* const* d_in, const int* in_sizes, int n_in,
                              void* d_out, int out_size, void* d_ws, size_t ws_size,
                              hipStream_t stream)
{
    const float* x  = (const float*)d_in[0];   // (8,64,128,128)
    const float* w  = (const float*)d_in[1];   // (64,64,3,3)
    const float* ow = (const float*)d_in[2];   // (18,64,5,5)
    const float* ob = (const float*)d_in[3];   // (18,)
    float* out = (float*)d_out;                // (8,64,128,128)

    // workspace layout: off (B,18,H,W) fp32 = 9,437,184 B ; wt (9,64,64) fp32
    float* off = (float*)d_ws;
    float* wt  = (float*)((char*)d_ws + (size_t)BB * OCC * HH * WW * 4);

    transpose_w_kernel<<<dim3((CC * 64 * 9 + 255) / 256), 256, 0, stream>>>(w, wt);
    offset_conv_kernel<<<dim3(BB * HH), 256, 0, stream>>>(x, ow, ob, off);
    deform_kernel<<<dim3(BB * HH), 256, 0, stream>>>(x, wt, off, out);
}

// Round 3
// 714.603 us; speedup vs baseline: 1.7599x; 1.3689x over previous
//
#include <hip/hip_runtime.h>

#define BB  8
#define CC  64
#define HH  128
#define WW  128
#define OCC 18   // 2*KK offset channels
// kernel K=3, KK=9 taps; offset conv is 5x5 pad 2

// ---------------------------------------------------------------------------
// Tiny kernel: transpose weights (o,c,kk) -> wt[t][c][o] so the einsum inner
// loop reads 8 consecutive floats per (t,c) (coalesced + L1-resident 16KB/tap)
// ---------------------------------------------------------------------------
__global__ __launch_bounds__(256) void transpose_w_kernel(
    const float* __restrict__ w, float* __restrict__ wt)
{
    int idx = blockIdx.x * 256 + threadIdx.x;   // over 64*64*9 = 36864
    if (idx >= CC * 64 * 9) return;
    int o = idx / (64 * 9);
    int r = idx % (64 * 9);
    int c = r / 9;
    int t = r % 9;
    wt[(t * 64 + c) * 64 + o] = w[idx];
}

// ---------------------------------------------------------------------------
// Offset conv: 5x5, C=64 -> 18, zero pad 2, + bias, clip to [-1,1].
// Block = one (b,y) row for ALL 18 oc. Per channel c: double-buffered 5x132
// zero-padded LDS tile (one barrier/c, prefetch overlapped with compute).
// oc0 forced to SGPR via readfirstlane => all weight/bias reads are s_loads.
// ---------------------------------------------------------------------------
__global__ __launch_bounds__(256) void offset_conv_kernel(
    const float* __restrict__ x, const float* __restrict__ ow,
    const float* __restrict__ ob, float* __restrict__ off)
{
    __shared__ float S[2][5 * 132];   // 2 x 2640 B, double-buffered

    const int tid = threadIdx.x;
    const int y = blockIdx.x & 127;
    const int b = blockIdx.x >> 7;

    // --- staging plan: 660 tile elements over 256 threads, 3 slots, all
    //     c-invariant except the channel base pointer
    int   srcoff[3]; float msk[3]; int ldso[3];
#pragma unroll
    for (int k = 0; k < 3; k++) {
        int idx = tid + k * 256;
        if (idx < 5 * 132) {
            int r   = idx / 132;
            int col = idx % 132;
            int yy = y + r - 2;
            int xx = col - 2;
            bool valid = (yy >= 0 && yy < HH && xx >= 0 && xx < WW);
            int yyc = yy < 0 ? 0 : (yy > HH - 1 ? HH - 1 : yy);
            int xxc = xx < 0 ? 0 : (xx > WW - 1 ? WW - 1 : xx);
            srcoff[k] = yyc * WW + xxc;
            msk[k]    = valid ? 1.f : 0.f;
            ldso[k]   = idx;
        } else { ldso[k] = -1; srcoff[k] = 0; msk[k] = 0.f; }
    }

    const int px = tid & 127;
    // CRITICAL: force SGPR so weight reads compile to s_load (round-2 bug:
    // compiler can't prove tid>>7 wave-uniform -> 225 vector loads per c)
    const int oc0 = __builtin_amdgcn_readfirstlane((tid >> 7) * 9);

    float acc[9];
#pragma unroll
    for (int i = 0; i < 9; i++) acc[i] = ob[oc0 + i];

    const float* xb = x + (size_t)b * CC * HH * WW;

    // prefetch + stage channel 0 into S[0]
    {
        float pf[3];
#pragma unroll
        for (int k = 0; k < 3; k++) pf[k] = xb[srcoff[k]];
#pragma unroll
        for (int k = 0; k < 3; k++)
            if (ldso[k] >= 0) S[0][ldso[k]] = pf[k] * msk[k];
    }

    for (int c = 0; c < CC; c++) {
        __syncthreads();   // S[c&1] staged & previous reads done

        // issue next channel's loads NOW; consume after compute (latency hide)
        float pf[3];
        if (c + 1 < CC) {
            const float* xn = xb + (size_t)(c + 1) * HH * WW;
#pragma unroll
            for (int k = 0; k < 3; k++) pf[k] = xn[srcoff[k]];
        }

        const float* Sc = S[c & 1];
        const float* wc = ow + ((size_t)oc0 * CC + c) * 25;  // SGPR base
#pragma unroll
        for (int ky = 0; ky < 5; ky++) {
            float v[5];
#pragma unroll
            for (int kx = 0; kx < 5; kx++) v[kx] = Sc[ky * 132 + px + kx];
#pragma unroll
            for (int i = 0; i < 9; i++) {
                const float* wr = wc + i * (CC * 25) + ky * 5;  // s_load
#pragma unroll
                for (int kx = 0; kx < 5; kx++)
                    acc[i] += v[kx] * wr[kx];
            }
        }

        if (c + 1 < CC) {
#pragma unroll
            for (int k = 0; k < 3; k++)
                if (ldso[k] >= 0) S[(c + 1) & 1][ldso[k]] = pf[k] * msk[k];
        }
    }

    const size_t obase = (((size_t)b * OCC + oc0) * HH + y) * WW + px;
#pragma unroll
    for (int i = 0; i < 9; i++) {
        float r = fminf(fmaxf(acc[i], -1.f), 1.f);
        off[obase + (size_t)i * HH * WW] = r;
    }
}

// ---------------------------------------------------------------------------
// Deformable sampling + einsum. One block per (b, y-row): 128 pixels.
// Per tap t: stage bilinear samples S[c][p] (64x128 fp32, 32KB LDS), then
// mini-GEMM: acc[o 8][p 4] += wt[t][c][o] * S[c][p] over c.
// ---------------------------------------------------------------------------
__global__ __launch_bounds__(256) void deform_kernel(
    const float* __restrict__ x, const float* __restrict__ wt,
    const float* __restrict__ off, float* __restrict__ out)
{
    __shared__ float S[CC * WW];   // 32 KB

    const int tid = threadIdx.x;
    const int b = blockIdx.x >> 7;
    const int y = blockIdx.x & 127;

    // staging role: pixel p, channel half
    const int p     = tid & 127;
    const int chalf = (tid >> 7) * 32;   // 0 or 32

    // einsum role: 8 o-groups x 32 pixel-groups
    const int og = tid >> 5;
    const int o0 = og * 8;
    const int pg = tid & 31;
    const int p4 = pg * 4;

    float acc[8][4];
#pragma unroll
    for (int i = 0; i < 8; i++)
#pragma unroll
        for (int j = 0; j < 4; j++) acc[i][j] = 0.f;

    const float* xb = x + (size_t)b * CC * HH * WW;

    for (int t = 0; t < 9; t++) {
        // ---- bilinear coords for (t, pixel p) — shared by all 64 channels
        float dy = off[(((size_t)(b * OCC + 2 * t    ) * HH + y) << 7) + p];
        float dx = off[(((size_t)(b * OCC + 2 * t + 1) * HH + y) << 7) + p];
        float py = (float)(y + t / 3 - 1) + dy;
        float px = (float)(p + t % 3 - 1) + dx;
        float y0f = floorf(py), x0f = floorf(px);
        float fy = py - y0f, fx = px - x0f;
        int y0 = (int)y0f, xi0 = (int)x0f;
        int y1 = y0 + 1,   xi1 = xi0 + 1;
        float vy0 = (y0  >= 0 && y0  < HH) ? 1.f : 0.f;
        float vy1 = (y1  >= 0 && y1  < HH) ? 1.f : 0.f;
        float vx0 = (xi0 >= 0 && xi0 < WW) ? 1.f : 0.f;
        float vx1 = (xi1 >= 0 && xi1 < WW) ? 1.f : 0.f;
        float gy = 1.f - fy, gx = 1.f - fx;
        float w00 = gy * gx * vy0 * vx0;
        float w01 = gy * fx * vy0 * vx1;
        float w10 = fy * gx * vy1 * vx0;
        float w11 = fy * fx * vy1 * vx1;
        int y0c = y0  < 0 ? 0 : (y0  > HH - 1 ? HH - 1 : y0);
        int y1c = y1  < 0 ? 0 : (y1  > HH - 1 ? HH - 1 : y1);
        int x0c = xi0 < 0 ? 0 : (xi0 > WW - 1 ? WW - 1 : xi0);
        int x1c = xi1 < 0 ? 0 : (xi1 > WW - 1 ? WW - 1 : xi1);
        int i00 = y0c * WW + x0c, i01 = y0c * WW + x1c;
        int i10 = y1c * WW + x0c, i11 = y1c * WW + x1c;

        // ---- stage 32 channels' samples for this pixel into LDS
        const float* img = xb + (size_t)chalf * HH * WW;
#pragma unroll 4
        for (int i = 0; i < 32; i++) {
            float v = w00 * img[i00] + w01 * img[i01]
                    + w10 * img[i10] + w11 * img[i11];
            S[(chalf + i) * WW + p] = v;
            img += HH * WW;
        }
        __syncthreads();

        // ---- mini-GEMM for this tap: acc += wt[t][c][o-tile] * S[c][p-tile]
        const float* wtt = wt + t * CC * 64;
        for (int c = 0; c < CC; c++) {
            float4 s = *(const float4*)&S[c * WW + p4];
            const float4* wp = (const float4*)(wtt + c * 64 + o0);
            float4 wa = wp[0], wb2 = wp[1];
            float wv[8] = {wa.x, wa.y, wa.z, wa.w, wb2.x, wb2.y, wb2.z, wb2.w};
#pragma unroll
            for (int oo = 0; oo < 8; oo++) {
                acc[oo][0] += wv[oo] * s.x;
                acc[oo][1] += wv[oo] * s.y;
                acc[oo][2] += wv[oo] * s.z;
                acc[oo][3] += wv[oo] * s.w;
            }
        }
        __syncthreads();   // before next tap overwrites S
    }

#pragma unroll
    for (int oo = 0; oo < 8; oo++) {
        float4 v;
        v.x = acc[oo][0]; v.y = acc[oo][1]; v.z = acc[oo][2]; v.w = acc[oo][3];
        *(float4*)&out[(((size_t)(b * CC + o0 + oo) * HH + y) << 7) + p4] = v;
    }
}

// ---------------------------------------------------------------------------
extern "C" void kernel_launch(void* const* d_in, const int* in_sizes, int n_in,
                              void* d_out, int out_size, void* d_ws, size_t ws_size,
                              hipStream_t stream)
{
    const float* x  = (const float*)d_in[0];   // (8,64,128,128)
    const float* w  = (const float*)d_in[1];   // (64,64,3,3)
    const float* ow = (const float*)d_in[2];   // (18,64,5,5)
    const float* ob = (const float*)d_in[3];   // (18,)
    float* out = (float*)d_out;                // (8,64,128,128)

    // workspace layout: off (B,18,H,W) fp32 = 9,437,184 B ; wt (9,64,64) fp32
    float* off = (float*)d_ws;
    float* wt  = (float*)((char*)d_ws + (size_t)BB * OCC * HH * WW * 4);

    transpose_w_kernel<<<dim3((CC * 64 * 9 + 255) / 256), 256, 0, stream>>>(w, wt);
    offset_conv_kernel<<<dim3(BB * HH), 256, 0, stream>>>(x, ow, ob, off);
    deform_kernel<<<dim3(BB * HH), 256, 0, stream>>>(x, wt, off, out);
}

// Round 4
// 496.196 us; speedup vs baseline: 2.5345x; 1.4402x over previous
//
#include <hip/hip_runtime.h>

#define BB  8
#define CC  64
#define HH  128
#define WW  128
#define OCC 18   // 2*KK offset channels

typedef __attribute__((ext_vector_type(8)))  short bf16x8;
typedef __attribute__((ext_vector_type(16))) float f32x16;

static __device__ __forceinline__ ushort f2bf(float f) {
    union { float f; unsigned u; } v; v.f = f;
    unsigned r = (v.u + 0x7FFFu + ((v.u >> 16) & 1u)) >> 16;  // RNE
    return (ushort)r;
}

// ---------------------------------------------------------------------------
// wt[t][c][o] for the deform einsum (unchanged)
// ---------------------------------------------------------------------------
__global__ __launch_bounds__(256) void transpose_w_kernel(
    const float* __restrict__ w, float* __restrict__ wt)
{
    int idx = blockIdx.x * 256 + threadIdx.x;
    if (idx >= CC * 64 * 9) return;
    int o = idx / (64 * 9);
    int r = idx % (64 * 9);
    int c = r / 9;
    int t = r % 9;
    wt[(t * 64 + c) * 64 + o] = w[idx];
}

// ---------------------------------------------------------------------------
// WA[t 25][oc 32][c 64] bf16 from ow (18,64,5,5); oc>=18 zero-padded
// ---------------------------------------------------------------------------
__global__ __launch_bounds__(256) void wa_kernel(
    const float* __restrict__ ow, ushort* __restrict__ WA)
{
    int idx = blockIdx.x * 256 + threadIdx.x;   // 25*32*64 = 51200
    if (idx >= 25 * 32 * 64) return;
    int t  = idx >> 11;
    int oc = (idx >> 6) & 31;
    int c  = idx & 63;
    float v = (oc < OCC) ? ow[((size_t)(oc * CC + c)) * 25 + t] : 0.f;
    WA[idx] = f2bf(v);
}

// ---------------------------------------------------------------------------
// XT[b][y' 132][x' 132][c 64] bf16, zero-padded 2 on all sides (y'=y+2).
// Interior blocks: LDS-transpose one (b,y) row. Extra 32 blocks: zero the
// top/bottom border rows. X-borders zeroed by interior blocks.
// ---------------------------------------------------------------------------
#define XTP 68   // LDS pitch in shorts: 136 B = 8B-aligned, bank stride 34%32=2 (free)
__global__ __launch_bounds__(256) void xt_kernel(
    const float* __restrict__ x, ushort* __restrict__ XT)
{
    __shared__ ushort T[128 * XTP];
    const int tid = threadIdx.x;

    if (blockIdx.x >= BB * HH) {                  // y-border zero rows
        int idx = blockIdx.x - BB * HH;           // 0..31
        int b = idx >> 2;
        int rsel = idx & 3;
        int yp = (rsel < 2) ? rsel : (128 + rsel); // {0,1,130,131}
        uint4* row = (uint4*)(XT + ((size_t)b * 132 + yp) * 132 * 64);
        for (int i = tid; i < 1056; i += 256) row[i] = make_uint4(0, 0, 0, 0);
        return;
    }

    const int y  = blockIdx.x & 127;
    const int b  = blockIdx.x >> 7;
    const int px = tid & 127;
    const int ch = tid >> 7;

    const float* xb = x + (size_t)b * CC * HH * WW + (size_t)y * WW;
#pragma unroll
    for (int i = 0; i < 32; i++) {
        int c = i * 2 + ch;
        T[px * XTP + c] = f2bf(xb[(size_t)c * HH * WW + px]);
    }
    __syncthreads();

    ushort* orow = XT + (((size_t)b * 132 + (y + 2)) * 132) * 64;

    if (tid < 32) {                               // x' in {0,1,130,131}: zeros
        int pb = tid >> 3;
        int pxp = (pb < 2) ? pb : (128 + pb);
        ((uint4*)(orow + (size_t)pxp * 64))[tid & 7] = make_uint4(0, 0, 0, 0);
    }

#pragma unroll
    for (int g = 0; g < 4; g++) {                 // interior: x' = px+2
        int idx = g * 256 + tid;                  // 1024 chunks of 8 shorts
        int p = idx >> 3;
        int part = idx & 7;
        uint2 lo = *(const uint2*)&T[p * XTP + part * 8];
        uint2 hi = *(const uint2*)&T[p * XTP + part * 8 + 4];
        uint4 wv; wv.x = lo.x; wv.y = lo.y; wv.z = hi.x; wv.w = hi.y;
        ((uint4*)(orow + ((size_t)(p + 2)) * 64))[part] = wv;
    }
}

// ---------------------------------------------------------------------------
// Offset conv as 25 shifted GEMMs on MFMA. Wave = 32oc x 32px tile; block =
// one (b,y) row (4 waves). 100 x mfma_32x32x16_bf16, operands from global
// (A L1-resident, B rows reused 20x in L1). Bias+clip epilogue, oc<18 stored.
// ---------------------------------------------------------------------------
__global__ __launch_bounds__(256) void offset_mfma_kernel(
    const ushort* __restrict__ XT, const ushort* __restrict__ WA,
    const float* __restrict__ ob, float* __restrict__ off)
{
    const int tid  = threadIdx.x;
    const int lane = tid & 63;
    const int n    = lane & 31;       // px within tile / oc for A
    const int h    = lane >> 5;       // k-half
    const int px0  = (tid >> 6) * 32;
    const int y = blockIdx.x & 127;
    const int b = blockIdx.x >> 7;

    f32x16 acc = {};

    // padded coords cancel: image row y+ky-2 -> y' = y+ky; col px+kx-2 -> x' = px+kx
    const ushort* rb0 = XT + (((size_t)b * 132 + y) * 132 + px0 + n) * 64 + h * 8;
    const ushort* ap  = WA + ((size_t)n) * 64 + h * 8;   // n = oc for A operand

#pragma unroll
    for (int t = 0; t < 25; t++) {
        const int ky = t / 5, kx = t % 5;
        const ushort* bp = rb0 + ((size_t)ky * 132 + kx) * 64;
        const ushort* at = ap + (size_t)t * 32 * 64;
#pragma unroll
        for (int cs = 0; cs < 4; cs++) {
            bf16x8 afrag = *(const bf16x8*)(at + cs * 16);
            bf16x8 bfrag = *(const bf16x8*)(bp + cs * 16);
            acc = __builtin_amdgcn_mfma_f32_32x32x16_bf16(afrag, bfrag, acc, 0, 0, 0);
        }
    }

    const int px = px0 + n;
#pragma unroll
    for (int r = 0; r < 16; r++) {
        int oc = (r & 3) + 8 * (r >> 2) + 4 * h;   // verified C/D mapping
        if (oc < OCC) {
            float v = acc[r] + ob[oc];
            v = fminf(fmaxf(v, -1.f), 1.f);
            off[(((size_t)b * OCC + oc) * HH + y) * WW + px] = v;
        }
    }
}

// ---------------------------------------------------------------------------
// Deformable sampling + einsum (unchanged from round 3)
// ---------------------------------------------------------------------------
__global__ __launch_bounds__(256) void deform_kernel(
    const float* __restrict__ x, const float* __restrict__ wt,
    const float* __restrict__ off, float* __restrict__ out)
{
    __shared__ float S[CC * WW];   // 32 KB

    const int tid = threadIdx.x;
    const int b = blockIdx.x >> 7;
    const int y = blockIdx.x & 127;

    const int p     = tid & 127;
    const int chalf = (tid >> 7) * 32;

    const int og = tid >> 5;
    const int o0 = og * 8;
    const int pg = tid & 31;
    const int p4 = pg * 4;

    float acc[8][4];
#pragma unroll
    for (int i = 0; i < 8; i++)
#pragma unroll
        for (int j = 0; j < 4; j++) acc[i][j] = 0.f;

    const float* xb = x + (size_t)b * CC * HH * WW;

    for (int t = 0; t < 9; t++) {
        float dy = off[(((size_t)(b * OCC + 2 * t    ) * HH + y) << 7) + p];
        float dx = off[(((size_t)(b * OCC + 2 * t + 1) * HH + y) << 7) + p];
        float py = (float)(y + t / 3 - 1) + dy;
        float px = (float)(p + t % 3 - 1) + dx;
        float y0f = floorf(py), x0f = floorf(px);
        float fy = py - y0f, fx = px - x0f;
        int y0 = (int)y0f, xi0 = (int)x0f;
        int y1 = y0 + 1,   xi1 = xi0 + 1;
        float vy0 = (y0  >= 0 && y0  < HH) ? 1.f : 0.f;
        float vy1 = (y1  >= 0 && y1  < HH) ? 1.f : 0.f;
        float vx0 = (xi0 >= 0 && xi0 < WW) ? 1.f : 0.f;
        float vx1 = (xi1 >= 0 && xi1 < WW) ? 1.f : 0.f;
        float gy = 1.f - fy, gx = 1.f - fx;
        float w00 = gy * gx * vy0 * vx0;
        float w01 = gy * fx * vy0 * vx1;
        float w10 = fy * gx * vy1 * vx0;
        float w11 = fy * fx * vy1 * vx1;
        int y0c = y0  < 0 ? 0 : (y0  > HH - 1 ? HH - 1 : y0);
        int y1c = y1  < 0 ? 0 : (y1  > HH - 1 ? HH - 1 : y1);
        int x0c = xi0 < 0 ? 0 : (xi0 > WW - 1 ? WW - 1 : xi0);
        int x1c = xi1 < 0 ? 0 : (xi1 > WW - 1 ? WW - 1 : xi1);
        int i00 = y0c * WW + x0c, i01 = y0c * WW + x1c;
        int i10 = y1c * WW + x0c, i11 = y1c * WW + x1c;

        const float* img = xb + (size_t)chalf * HH * WW;
#pragma unroll 4
        for (int i = 0; i < 32; i++) {
            float v = w00 * img[i00] + w01 * img[i01]
                    + w10 * img[i10] + w11 * img[i11];
            S[(chalf + i) * WW + p] = v;
            img += HH * WW;
        }
        __syncthreads();

        const float* wtt = wt + t * CC * 64;
        for (int c = 0; c < CC; c++) {
            float4 s = *(const float4*)&S[c * WW + p4];
            const float4* wp = (const float4*)(wtt + c * 64 + o0);
            float4 wa = wp[0], wb2 = wp[1];
            float wv[8] = {wa.x, wa.y, wa.z, wa.w, wb2.x, wb2.y, wb2.z, wb2.w};
#pragma unroll
            for (int oo = 0; oo < 8; oo++) {
                acc[oo][0] += wv[oo] * s.x;
                acc[oo][1] += wv[oo] * s.y;
                acc[oo][2] += wv[oo] * s.z;
                acc[oo][3] += wv[oo] * s.w;
            }
        }
        __syncthreads();
    }

#pragma unroll
    for (int oo = 0; oo < 8; oo++) {
        float4 v;
        v.x = acc[oo][0]; v.y = acc[oo][1]; v.z = acc[oo][2]; v.w = acc[oo][3];
        *(float4*)&out[(((size_t)(b * CC + o0 + oo) * HH + y) << 7) + p4] = v;
    }
}

// ---------------------------------------------------------------------------
extern "C" void kernel_launch(void* const* d_in, const int* in_sizes, int n_in,
                              void* d_out, int out_size, void* d_ws, size_t ws_size,
                              hipStream_t stream)
{
    const float* x  = (const float*)d_in[0];   // (8,64,128,128)
    const float* w  = (const float*)d_in[1];   // (64,64,3,3)
    const float* ow = (const float*)d_in[2];   // (18,64,5,5)
    const float* ob = (const float*)d_in[3];   // (18,)
    float* out = (float*)d_out;                // (8,64,128,128)

    // workspace: off 9,437,184 | wt 147,456 | XT 17,842,176 | WA 102,400
    float*  off = (float*)d_ws;
    float*  wt  = (float*)((char*)d_ws + 9437184);
    ushort* XT  = (ushort*)((char*)d_ws + 9584640);
    ushort* WA  = (ushort*)((char*)d_ws + 27426816);

    transpose_w_kernel<<<144, 256, 0, stream>>>(w, wt);
    wa_kernel<<<200, 256, 0, stream>>>(ow, WA);
    xt_kernel<<<BB * HH + 32, 256, 0, stream>>>(x, XT);
    offset_mfma_kernel<<<BB * HH, 256, 0, stream>>>(XT, WA, ob, off);
    deform_kernel<<<BB * HH, 256, 0, stream>>>(x, wt, off, out);
}

// Round 5
// 275.933 us; speedup vs baseline: 4.5576x; 1.7982x over previous
//
#include <hip/hip_runtime.h>

#define BB  8
#define CC  64
#define HH  128
#define WW  128
#define OCC 18   // 2*KK offset channels
#define XP  133  // padded spatial dim (pad 2 low, 3 high: offsets clipped to +-1)
#define SP  72   // deform LDS pitch in shorts: 144B = 16B-aligned, word stride 36%32=4 (conflict-free b128)

typedef __attribute__((ext_vector_type(8)))  short bf16x8;
typedef __attribute__((ext_vector_type(16))) float f32x16;

static __device__ __forceinline__ ushort f2bf(float f) {
    union { float f; unsigned u; } v; v.f = f;
    unsigned r = (v.u + 0x7FFFu + ((v.u >> 16) & 1u)) >> 16;  // RNE
    return (ushort)r;
}
static __device__ __forceinline__ float bfu(unsigned u) {
    union { unsigned u; float f; } v; v.u = u; return v.f;
}

// ---------------------------------------------------------------------------
// WA[t 25][oc 32][c 64] bf16 from ow (18,64,5,5); oc>=18 zero-padded
// ---------------------------------------------------------------------------
__global__ __launch_bounds__(256) void wa_kernel(
    const float* __restrict__ ow, ushort* __restrict__ WA)
{
    int idx = blockIdx.x * 256 + threadIdx.x;   // 25*32*64 = 51200
    if (idx >= 25 * 32 * 64) return;
    int t  = idx >> 11;
    int oc = (idx >> 6) & 31;
    int c  = idx & 63;
    float v = (oc < OCC) ? ow[((size_t)(oc * CC + c)) * 25 + t] : 0.f;
    WA[idx] = f2bf(v);
}

// ---------------------------------------------------------------------------
// WD[t 9][o 64][c 64] bf16 from w (64,64,3,3): A-operand for deform GEMM
// ---------------------------------------------------------------------------
__global__ __launch_bounds__(256) void wd_kernel(
    const float* __restrict__ w, ushort* __restrict__ WD)
{
    int idx = blockIdx.x * 256 + threadIdx.x;   // 9*64*64 = 36864
    if (idx >= 9 * 64 * 64) return;
    int t = idx >> 12;
    int o = (idx >> 6) & 63;
    int c = idx & 63;
    WD[idx] = f2bf(w[((size_t)(o * CC + c)) * 9 + t]);
}

// ---------------------------------------------------------------------------
// XT[b][y' XP][x' XP][c 64] bf16, zero-padded (y'=y+2, x'=x+2; rows/cols
// {0,1,130,131,132} are zero). Interior blocks transpose one (b,y) row via
// LDS; 40 extra blocks zero the border rows.
// ---------------------------------------------------------------------------
#define XTP 68   // transpose-LDS pitch (8B-aligned, bank stride 2 => free)
__global__ __launch_bounds__(256) void xt_kernel(
    const float* __restrict__ x, ushort* __restrict__ XT)
{
    __shared__ ushort T[128 * XTP];
    const int tid = threadIdx.x;

    if (blockIdx.x >= BB * HH) {                  // y-border zero rows
        int idx = blockIdx.x - BB * HH;           // 0..39
        int b = idx / 5;
        int r = idx % 5;
        int yp = (r < 2) ? r : (128 + r);         // {0,1,130,131,132}
        uint4* row = (uint4*)(XT + ((size_t)b * XP + yp) * XP * 64);
        for (int i = tid; i < XP * 8; i += 256) row[i] = make_uint4(0, 0, 0, 0);
        return;
    }

    const int y  = blockIdx.x & 127;
    const int b  = blockIdx.x >> 7;
    const int px = tid & 127;
    const int ch = tid >> 7;

    const float* xb = x + (size_t)b * CC * HH * WW + (size_t)y * WW;
#pragma unroll
    for (int i = 0; i < 32; i++) {
        int c = i * 2 + ch;
        T[px * XTP + c] = f2bf(xb[(size_t)c * HH * WW + px]);
    }
    __syncthreads();

    ushort* orow = XT + (((size_t)b * XP + (y + 2)) * XP) * 64;

    if (tid < 40) {                               // x' in {0,1,130,131,132}: zeros
        int pb = tid >> 3;
        int col = (pb < 2) ? pb : (128 + pb);
        ((uint4*)(orow + (size_t)col * 64))[tid & 7] = make_uint4(0, 0, 0, 0);
    }

#pragma unroll
    for (int g = 0; g < 4; g++) {                 // interior: x' = px+2
        int idx = g * 256 + tid;                  // 1024 chunks of 8 shorts
        int p = idx >> 3;
        int part = idx & 7;
        uint2 lo = *(const uint2*)&T[p * XTP + part * 8];
        uint2 hi = *(const uint2*)&T[p * XTP + part * 8 + 4];
        uint4 wv; wv.x = lo.x; wv.y = lo.y; wv.z = hi.x; wv.w = hi.y;
        ((uint4*)(orow + ((size_t)(p + 2)) * 64))[part] = wv;
    }
}

// ---------------------------------------------------------------------------
// Offset conv as 25 shifted GEMMs on MFMA (unchanged except XP pitch).
// ---------------------------------------------------------------------------
__global__ __launch_bounds__(256) void offset_mfma_kernel(
    const ushort* __restrict__ XT, const ushort* __restrict__ WA,
    const float* __restrict__ ob, float* __restrict__ off)
{
    const int tid  = threadIdx.x;
    const int lane = tid & 63;
    const int n    = lane & 31;
    const int h    = lane >> 5;
    const int px0  = (tid >> 6) * 32;
    const int y = blockIdx.x & 127;
    const int b = blockIdx.x >> 7;

    f32x16 acc = {};

    const ushort* rb0 = XT + (((size_t)b * XP + y) * XP + px0 + n) * 64 + h * 8;
    const ushort* ap  = WA + ((size_t)n) * 64 + h * 8;

#pragma unroll
    for (int t = 0; t < 25; t++) {
        const int ky = t / 5, kx = t % 5;
        const ushort* bp = rb0 + ((size_t)ky * XP + kx) * 64;
        const ushort* at = ap + (size_t)t * 32 * 64;
#pragma unroll
        for (int cs = 0; cs < 4; cs++) {
            bf16x8 afrag = *(const bf16x8*)(at + cs * 16);
            bf16x8 bfrag = *(const bf16x8*)(bp + cs * 16);
            acc = __builtin_amdgcn_mfma_f32_32x32x16_bf16(afrag, bfrag, acc, 0, 0, 0);
        }
    }

    const int px = px0 + n;
#pragma unroll
    for (int r = 0; r < 16; r++) {
        int oc = (r & 3) + 8 * (r >> 2) + 4 * h;
        if (oc < OCC) {
            float v = acc[r] + ob[oc];
            v = fminf(fmaxf(v, -1.f), 1.f);
            off[(((size_t)b * OCC + oc) * HH + y) * WW + px] = v;
        }
    }
}

// ---------------------------------------------------------------------------
// Deformable sample + einsum on MFMA. Block = (b,y) row. Per tap: gather
// bilinear bf16 samples from XT (channel-innermost, zero-padded => no masks,
// 16B loads cover 8 channels), stage S[p 128][c 64] in LDS, then GEMM:
// out[64 o][128 px] += WD[t] (A, 64x64) x S (B, 64x128). Wave w: m0=(w&1)*32,
// n-tiles (w>>1)*64 + {0,32}; 8 mfma_32x32x16 per tap per wave.
// ---------------------------------------------------------------------------
__global__ __launch_bounds__(256) void deform_mfma_kernel(
    const ushort* __restrict__ XT, const ushort* __restrict__ WD,
    const float* __restrict__ off, float* __restrict__ out)
{
    __shared__ ushort S[128 * SP];   // 18432 B

    const int tid  = threadIdx.x;
    const int lane = tid & 63;
    const int n    = lane & 31;
    const int h    = lane >> 5;
    const int w    = tid >> 6;
    const int m0   = (w & 1) * 32;
    const int n0   = (w >> 1) * 64;
    const int y = blockIdx.x & 127;
    const int b = blockIdx.x >> 7;

    const int p     = tid & 127;          // gather pixel
    const int chalf = (tid >> 7) * 32;    // gather channel half

    f32x16 acc0 = {}, acc1 = {};

    const ushort* xtb = XT + (size_t)b * XP * XP * 64;
    const size_t  offb = ((size_t)b * OCC * HH + y) * WW + p;

    for (int t = 0; t < 9; t++) {
        // ---- bilinear setup (offsets clipped to [-1,1] => corners in pad)
        float dy = off[offb + (size_t)(2 * t)     * HH * WW];
        float dx = off[offb + (size_t)(2 * t + 1) * HH * WW];
        float py = (float)(y + t / 3 - 1) + dy;
        float px = (float)(p + t % 3 - 1) + dx;
        float y0f = floorf(py), x0f = floorf(px);
        float fy = py - y0f, fx = px - x0f;
        int iy = (int)y0f + 2, ix = (int)x0f + 2;
        float w00 = (1.f - fy) * (1.f - fx), w01 = (1.f - fy) * fx;
        float w10 = fy * (1.f - fx),         w11 = fy * fx;

        const ushort* c00 = xtb + ((size_t)iy * XP + ix) * 64 + chalf;
        const ushort* c10 = c00 + XP * 64;

        if (t) __syncthreads();   // all waves done reading S[t-1]

#pragma unroll
        for (int k = 0; k < 4; k++) {
            uint4 q00 = *(const uint4*)(c00 + k * 8);
            uint4 q01 = *(const uint4*)(c00 + 64 + k * 8);
            uint4 q10 = *(const uint4*)(c10 + k * 8);
            uint4 q11 = *(const uint4*)(c10 + 64 + k * 8);
            unsigned o4[4];
#pragma unroll
            for (int j = 0; j < 4; j++) {
                unsigned u00 = ((const unsigned*)&q00)[j];
                unsigned u01 = ((const unsigned*)&q01)[j];
                unsigned u10 = ((const unsigned*)&q10)[j];
                unsigned u11 = ((const unsigned*)&q11)[j];
                float lo = w00 * bfu(u00 << 16) + w01 * bfu(u01 << 16)
                         + w10 * bfu(u10 << 16) + w11 * bfu(u11 << 16);
                float hi = w00 * bfu(u00 & 0xffff0000u) + w01 * bfu(u01 & 0xffff0000u)
                         + w10 * bfu(u10 & 0xffff0000u) + w11 * bfu(u11 & 0xffff0000u);
                o4[j] = (unsigned)f2bf(lo) | ((unsigned)f2bf(hi) << 16);
            }
            *(uint4*)&S[p * SP + chalf + k * 8] = *(uint4*)o4;
        }
        __syncthreads();

        // ---- GEMM for this tap
        const ushort* at  = WD + ((size_t)(t * 64 + m0 + n)) * 64 + h * 8;
        const ushort* b0p = &S[(n0 + n) * SP + h * 8];
        const ushort* b1p = &S[(n0 + 32 + n) * SP + h * 8];
#pragma unroll
        for (int cs = 0; cs < 4; cs++) {
            bf16x8 af  = *(const bf16x8*)(at  + cs * 16);
            bf16x8 bf0 = *(const bf16x8*)(b0p + cs * 16);
            bf16x8 bf1 = *(const bf16x8*)(b1p + cs * 16);
            acc0 = __builtin_amdgcn_mfma_f32_32x32x16_bf16(af, bf0, acc0, 0, 0, 0);
            acc1 = __builtin_amdgcn_mfma_f32_32x32x16_bf16(af, bf1, acc1, 0, 0, 0);
        }
    }

    // ---- epilogue: C/D layout col=lane&31, row=(r&3)+8*(r>>2)+4*h
#pragma unroll
    for (int r = 0; r < 16; r++) {
        int o = m0 + (r & 3) + 8 * (r >> 2) + 4 * h;
        size_t ob = ((size_t)(b * CC + o) * HH + y) * WW;
        out[ob + n0 + n]      = acc0[r];
        out[ob + n0 + 32 + n] = acc1[r];
    }
}

// ---------------------------------------------------------------------------
extern "C" void kernel_launch(void* const* d_in, const int* in_sizes, int n_in,
                              void* d_out, int out_size, void* d_ws, size_t ws_size,
                              hipStream_t stream)
{
    const float* x  = (const float*)d_in[0];   // (8,64,128,128)
    const float* w  = (const float*)d_in[1];   // (64,64,3,3)
    const float* ow = (const float*)d_in[2];   // (18,64,5,5)
    const float* ob = (const float*)d_in[3];   // (18,)
    float* out = (float*)d_out;                // (8,64,128,128)

    // workspace: XT 18,113,536 | off 9,437,184 | WA 102,400 | WD 73,728
    ushort* XT  = (ushort*)d_ws;
    float*  off = (float*)((char*)d_ws + 18113536);
    ushort* WA  = (ushort*)((char*)d_ws + 27550720);
    ushort* WD  = (ushort*)((char*)d_ws + 27653120);

    wa_kernel<<<200, 256, 0, stream>>>(ow, WA);
    wd_kernel<<<144, 256, 0, stream>>>(w, WD);
    xt_kernel<<<BB * HH + 40, 256, 0, stream>>>(x, XT);
    offset_mfma_kernel<<<BB * HH, 256, 0, stream>>>(XT, WA, ob, off);
    deform_mfma_kernel<<<BB * HH, 256, 0, stream>>>(XT, WD, off, out);
}